// Round 3
// baseline (336.294 us; speedup 1.0000x reference)
//
#include <hip/hip_runtime.h>
#include <stdint.h>

#define NLAYERS 3
#define NQ 8
#define DIM 256          // 2^NQ
#define KDIM 512         // 2*DIM (real+imag)
#define BM 64            // batch rows per block
#define AST 520          // A LDS stride in bf16 (512 + 8 pad -> free 2-way only)
#define NBLK (131072 / BM)

typedef float  f32x4  __attribute__((ext_vector_type(4)));
typedef __bf16 bf16x8 __attribute__((ext_vector_type(8)));

__device__ __forceinline__ unsigned short f2bf(float f){
    union { float f; uint32_t u; } v; v.f = f;
    uint32_t u = v.u;
    u += 0x7fffu + ((u >> 16) & 1u);   // round-to-nearest-even
    return (unsigned short)(u >> 16);
}

__device__ __forceinline__ float2 cmul(float2 a, float2 b){
    return make_float2(a.x*b.x - a.y*b.y, a.x*b.y + a.y*b.x);
}

// ---------------------------------------------------------------------------
// Kernel 1: build G (256x512 bf16, row-major [n][k]) from params.
// Block j simulates the circuit on basis state e_j in LDS.
// ---------------------------------------------------------------------------
__global__ __launch_bounds__(256) void build_g_kernel(const float* __restrict__ params,
                                                      unsigned short* __restrict__ G){
    __shared__ float2 st[2][DIM];
    __shared__ float2 gm[NLAYERS*NQ][4];   // U0a,U0b,U1a,U1b per gate
    const int j = blockIdx.x;
    const int i = threadIdx.x;

    if (i < NLAYERS*NQ){
        const float* pp = params + i*3;
        float hx = 0.5f*pp[0], hy = 0.5f*pp[1], hz = 0.5f*pp[2];
        float cx = cosf(hx), sx = sinf(hx);
        float cy = cosf(hy), sy = sinf(hy);
        float cz = cosf(hz), sz = sinf(hz);
        float2 ezm = make_float2(cz, -sz), ezp = make_float2(cz, sz);
        float2 m00 = make_float2( cy*cx,  sy*sx);
        float2 m01 = make_float2(-sy*cx, -cy*sx);
        float2 m10 = make_float2( sy*cx, -cy*sx);
        float2 m11 = make_float2( cy*cx, -sy*sx);
        gm[i][0] = cmul(ezm, m00);
        gm[i][1] = cmul(ezm, m01);
        gm[i][2] = cmul(ezp, m10);
        gm[i][3] = cmul(ezp, m11);
    }

    // composed CNOT-ring permutation (params-independent, same all layers)
    int psrc = i;
    #pragma unroll
    for (int q = NQ-1; q >= 0; --q){
        int c  = 7 - q;
        int tb = 7 - ((q + 1) & 7);
        psrc = ((psrc >> c) & 1) ? (psrc ^ (1 << tb)) : psrc;
    }

    int cur = 0;
    st[0][i] = make_float2(i == j ? 1.0f : 0.0f, 0.0f);
    __syncthreads();

    for (int l = 0; l < NLAYERS; ++l){
        for (int q = 0; q < NQ; ++q){
            float2 U0a = gm[l*NQ+q][0], U0b = gm[l*NQ+q][1];
            float2 U1a = gm[l*NQ+q][2], U1b = gm[l*NQ+q][3];
            int p  = 7 - q;
            int bs = (i >> p) & 1;
            int i0 = i & ~(1 << p), i1 = i | (1 << p);
            float2 a0 = st[cur][i0], a1 = st[cur][i1];
            float2 ua = bs ? U1a : U0a;
            float2 ub = bs ? U1b : U0b;
            float2 r;
            r.x = ua.x*a0.x - ua.y*a0.y + ub.x*a1.x - ub.y*a1.y;
            r.y = ua.x*a0.y + ua.y*a0.x + ub.x*a1.y + ub.y*a1.x;
            st[cur ^ 1][i] = r;
            cur ^= 1;
            __syncthreads();
        }
        float2 r = st[cur][psrc];
        st[cur ^ 1][i] = r;
        cur ^= 1;
        __syncthreads();
    }

    const int m = i & 127;
    float2 a = st[cur][m];
    unsigned short lo, hi;
    if (i < 128){ lo = f2bf(a.x); hi = f2bf(-a.y); }   // Wre | -Wim
    else        { lo = f2bf(a.y); hi = f2bf( a.x); }   // Wim |  Wre
    G[(size_t)i*KDIM + j]        = lo;
    G[(size_t)i*KDIM + j + DIM]  = hi;
}

// ---------------------------------------------------------------------------
// Kernel 2: out[m] = || G * [sr_m ; si_m] ||^2
// M=131072, N=256, K=512, mfma 16x16x32 bf16.
// Barrier-free K-loop: A (batch rows, converted bf16) staged ONCE in LDS in
// the prologue; B (G) fragments read directly from global (L2-resident,
// quads cover a full 64B line per row). One __syncthreads in the whole
// kernel before the K-loop; loads pipeline freely against MFMA.
// ---------------------------------------------------------------------------
__global__ __launch_bounds__(256, 2) void qform_kernel(const float* __restrict__ sr,
                                                       const float* __restrict__ si,
                                                       const unsigned short* __restrict__ G,
                                                       float* __restrict__ out){
    __shared__ unsigned short As[BM * AST];      // 66560 B
    __shared__ float red[4 * BM];                //  1 KB

    const int tid  = threadIdx.x;
    const int lane = tid & 63;
    const int w    = tid >> 6;        // wave 0..3
    const int l15  = lane & 15;
    const int quad = lane >> 4;       // 0..3
    const size_t mbase = (size_t)blockIdx.x * BM;

    // ---- prologue: stage A = [Z_re | Z_im] as bf16 into LDS (once, full K)
    {
        const int r  = tid >> 2;           // row 0..63
        const int cs = (tid & 3) * 64;     // fp32 col segment within a half
        #pragma unroll
        for (int h = 0; h < 2; ++h){
            const float* gp = (h ? si : sr) + (mbase + r)*DIM + cs;
            unsigned short* dst = &As[r*AST + h*256 + cs];
            #pragma unroll
            for (int o = 0; o < 8; ++o){
                float4 fa = ((const float4*)gp)[o*2];
                float4 fb = ((const float4*)gp)[o*2+1];
                uint4 pk;
                pk.x = f2bf(fa.x) | ((uint32_t)f2bf(fa.y) << 16);
                pk.y = f2bf(fa.z) | ((uint32_t)f2bf(fa.w) << 16);
                pk.z = f2bf(fb.x) | ((uint32_t)f2bf(fb.y) << 16);
                pk.w = f2bf(fb.z) | ((uint32_t)f2bf(fb.w) << 16);
                *(uint4*)(dst + o*8) = pk;
            }
        }
    }

    f32x4 acc[4][4];
    const f32x4 vzero = {0.0f, 0.0f, 0.0f, 0.0f};
    #pragma unroll
    for (int ii = 0; ii < 4; ++ii)
        #pragma unroll
        for (int jj = 0; jj < 4; ++jj)
            acc[ii][jj] = vzero;

    // per-lane B base: row = w*64 + jj*16 + l15, col granule = quad*8
    const unsigned short* gB = G + ((size_t)(w*64 + l15))*KDIM + quad*8;

    __syncthreads();   // the only barrier before the epilogue

    // ---- K-loop: 16 ksteps of 32, no barriers, no vmcnt(0) drains
    #pragma unroll 4
    for (int ks = 0; ks < 16; ++ks){
        bf16x8 a[4], b[4];
        #pragma unroll
        for (int jj = 0; jj < 4; ++jj)
            b[jj] = *(const bf16x8*)(gB + (size_t)jj*16*KDIM + ks*32);
        #pragma unroll
        for (int ii = 0; ii < 4; ++ii)
            a[ii] = *(const bf16x8*)&As[(ii*16 + l15)*AST + ks*32 + quad*8];
        #pragma unroll
        for (int ii = 0; ii < 4; ++ii)
            #pragma unroll
            for (int jj = 0; jj < 4; ++jj)
                acc[ii][jj] = __builtin_amdgcn_mfma_f32_16x16x32_bf16(
                    a[ii], b[jj], acc[ii][jj], 0, 0, 0);
    }

    // ---- epilogue: out[m] = sum_n Y[m][n]^2
    // C/D layout: n = jj*16 + l15, m = ii*16 + quad*4 + r
    float s[4][4];
    #pragma unroll
    for (int ii = 0; ii < 4; ++ii)
        #pragma unroll
        for (int r = 0; r < 4; ++r){
            float t = 0.0f;
            #pragma unroll
            for (int jj = 0; jj < 4; ++jj){ float v = acc[ii][jj][r]; t += v*v; }
            s[ii][r] = t;
        }
    #pragma unroll
    for (int ii = 0; ii < 4; ++ii)
        #pragma unroll
        for (int r = 0; r < 4; ++r){
            float t = s[ii][r];
            t += __shfl_xor(t, 1);
            t += __shfl_xor(t, 2);
            t += __shfl_xor(t, 4);
            t += __shfl_xor(t, 8);
            s[ii][r] = t;
        }
    if (l15 == 0){
        #pragma unroll
        for (int ii = 0; ii < 4; ++ii)
            #pragma unroll
            for (int r = 0; r < 4; ++r)
                red[w*64 + ii*16 + quad*4 + r] = s[ii][r];
    }
    __syncthreads();
    if (tid < 64){
        float o = red[tid] + red[64 + tid] + red[128 + tid] + red[192 + tid];
        out[mbase + tid] = o;
    }
}

extern "C" void kernel_launch(void* const* d_in, const int* in_sizes, int n_in,
                              void* d_out, int out_size, void* d_ws, size_t ws_size,
                              hipStream_t stream){
    const float* params = (const float*)d_in[0];
    const float* sr     = (const float*)d_in[1];
    const float* si     = (const float*)d_in[2];
    unsigned short* G   = (unsigned short*)d_ws;   // 256*512*2 = 256 KB
    float* out          = (float*)d_out;

    build_g_kernel<<<dim3(DIM), dim3(256), 0, stream>>>(params, G);
    qform_kernel<<<dim3(NBLK), dim3(256), 0, stream>>>(sr, si, G, out);
}

// Round 4
// 296.372 us; speedup vs baseline: 1.1347x; 1.1347x over previous
//
#include <hip/hip_runtime.h>
#include <stdint.h>

#define NLAYERS 3
#define NQ 8
#define DIM 256          // 2^NQ
#define KDIM 512         // 2*DIM (real+imag)
#define CCHUNKS 4        // 64-row chunks per block
#define GRID 512         // 512 blocks * 256 rows = 131072
#define AST 264          // A LDS row stride in bf16 (256 + 8 pad)

typedef float  f32x4  __attribute__((ext_vector_type(4)));
typedef __bf16 bf16x8 __attribute__((ext_vector_type(8)));

__device__ __forceinline__ unsigned short f2bf(float f){
    union { float f; uint32_t u; } v; v.f = f;
    uint32_t u = v.u;
    u += 0x7fffu + ((u >> 16) & 1u);   // round-to-nearest-even
    return (unsigned short)(u >> 16);
}

__device__ __forceinline__ float2 cmul(float2 a, float2 b){
    return make_float2(a.x*b.x - a.y*b.y, a.x*b.y + a.y*b.x);
}

// ---------------------------------------------------------------------------
// Kernel 1: build G (256x512 bf16, row-major [n][k]) from params.
// Block j simulates the circuit on basis state e_j in LDS.
// ---------------------------------------------------------------------------
__global__ __launch_bounds__(256) void build_g_kernel(const float* __restrict__ params,
                                                      unsigned short* __restrict__ G){
    __shared__ float2 st[2][DIM];
    __shared__ float2 gm[NLAYERS*NQ][4];   // U0a,U0b,U1a,U1b per gate
    const int j = blockIdx.x;
    const int i = threadIdx.x;

    if (i < NLAYERS*NQ){
        const float* pp = params + i*3;
        float hx = 0.5f*pp[0], hy = 0.5f*pp[1], hz = 0.5f*pp[2];
        float cx = cosf(hx), sx = sinf(hx);
        float cy = cosf(hy), sy = sinf(hy);
        float cz = cosf(hz), sz = sinf(hz);
        float2 ezm = make_float2(cz, -sz), ezp = make_float2(cz, sz);
        float2 m00 = make_float2( cy*cx,  sy*sx);
        float2 m01 = make_float2(-sy*cx, -cy*sx);
        float2 m10 = make_float2( sy*cx, -cy*sx);
        float2 m11 = make_float2( cy*cx, -sy*sx);
        gm[i][0] = cmul(ezm, m00);
        gm[i][1] = cmul(ezm, m01);
        gm[i][2] = cmul(ezp, m10);
        gm[i][3] = cmul(ezp, m11);
    }

    int psrc = i;                          // composed CNOT-ring permutation
    #pragma unroll
    for (int q = NQ-1; q >= 0; --q){
        int c  = 7 - q;
        int tb = 7 - ((q + 1) & 7);
        psrc = ((psrc >> c) & 1) ? (psrc ^ (1 << tb)) : psrc;
    }

    int cur = 0;
    st[0][i] = make_float2(i == j ? 1.0f : 0.0f, 0.0f);
    __syncthreads();

    for (int l = 0; l < NLAYERS; ++l){
        for (int q = 0; q < NQ; ++q){
            float2 U0a = gm[l*NQ+q][0], U0b = gm[l*NQ+q][1];
            float2 U1a = gm[l*NQ+q][2], U1b = gm[l*NQ+q][3];
            int p  = 7 - q;
            int bs = (i >> p) & 1;
            int i0 = i & ~(1 << p), i1 = i | (1 << p);
            float2 a0 = st[cur][i0], a1 = st[cur][i1];
            float2 ua = bs ? U1a : U0a;
            float2 ub = bs ? U1b : U0b;
            float2 r;
            r.x = ua.x*a0.x - ua.y*a0.y + ub.x*a1.x - ub.y*a1.y;
            r.y = ua.x*a0.y + ua.y*a0.x + ub.x*a1.y + ub.y*a1.x;
            st[cur ^ 1][i] = r;
            cur ^= 1;
            __syncthreads();
        }
        float2 r = st[cur][psrc];
        st[cur ^ 1][i] = r;
        cur ^= 1;
        __syncthreads();
    }

    const int m = i & 127;
    float2 a = st[cur][m];
    unsigned short lo, hi;
    if (i < 128){ lo = f2bf(a.x); hi = f2bf(-a.y); }   // Wre | -Wim
    else        { lo = f2bf(a.y); hi = f2bf( a.x); }   // Wim |  Wre
    G[(size_t)i*KDIM + j]        = lo;
    G[(size_t)i*KDIM + j + DIM]  = hi;
}

// ---------------------------------------------------------------------------
// Kernel 2 (streaming): out[m] = || G * [sr_m ; si_m] ||^2
// 512 threads = 8 waves. B (G) lives in registers: wave w holds n-rows
// [w*32,w*32+32) x K=512 (uint4 Breg[2][16] = 128 VGPRs). A double-buffered
// in LDS; next phase's global loads issued BEFORE current phase's compute so
// ~64 KB/CU stays outstanding continuously (HBM-saturating). One barrier per
// phase; drain cost ~0 (loads have a whole BW-bound phase to land).
// ---------------------------------------------------------------------------
__global__ __launch_bounds__(512, 2) void qform_kernel(const float* __restrict__ sr,
                                                       const float* __restrict__ si,
                                                       const unsigned short* __restrict__ G,
                                                       float* __restrict__ out){
    __shared__ unsigned short As[2][64][AST];   // 67584 B
    __shared__ float red[8][64];                //  2 KB

    const int tid  = threadIdx.x;
    const int lane = tid & 63;
    const int w    = tid >> 6;        // wave 0..7
    const int l15  = lane & 15;
    const int quad = lane >> 4;       // 0..3
    const int arow = tid >> 3;        // staging row 0..63
    const int sub  = tid & 7;         // staging k-subsegment
    const size_t mblock = (size_t)blockIdx.x * (CCHUNKS*64);

    // ---- issue A loads for chunk 0, half 0 (longest latency first)
    float4 L[8];
    {
        const float* gp = sr + (mblock + arow)*DIM + sub*8;
        #pragma unroll
        for (int o = 0; o < 4; ++o){
            L[2*o]   = *(const float4*)(gp + o*64);
            L[2*o+1] = *(const float4*)(gp + o*64 + 4);
        }
    }

    // ---- B into registers (L2/L3-resident, 32 KB per wave)
    uint4 Breg[2][16];
    {
        const unsigned short* gB = G + (size_t)(w*32 + l15)*KDIM + quad*8;
        #pragma unroll
        for (int jj = 0; jj < 2; ++jj)
            #pragma unroll
            for (int kg = 0; kg < 16; ++kg)
                Breg[jj][kg] = *(const uint4*)(gB + (size_t)jj*16*KDIM + kg*32);
    }

    f32x4 acc[4][2];
    const f32x4 vzero = {0.0f, 0.0f, 0.0f, 0.0f};
    #pragma unroll
    for (int ii = 0; ii < 4; ++ii){ acc[ii][0] = vzero; acc[ii][1] = vzero; }

    // convert+write staged loads into LDS buffer
    #define WRITE_A(buf)                                                        \
        {                                                                       \
            unsigned short* dst = &As[buf][arow][0];                            \
            _Pragma("unroll")                                                   \
            for (int o = 0; o < 4; ++o){                                        \
                float4 f0 = L[2*o], f1 = L[2*o+1];                              \
                uint4 pk;                                                       \
                pk.x = f2bf(f0.x) | ((uint32_t)f2bf(f0.y) << 16);               \
                pk.y = f2bf(f0.z) | ((uint32_t)f2bf(f0.w) << 16);               \
                pk.z = f2bf(f1.x) | ((uint32_t)f2bf(f1.y) << 16);               \
                pk.w = f2bf(f1.z) | ((uint32_t)f2bf(f1.w) << 16);               \
                *(uint4*)(dst + sub*8 + o*64) = pk;                             \
            }                                                                   \
        }

    #define ISSUE_A(Z, c)                                                       \
        {                                                                       \
            const float* gp = (Z) + (mblock + (c)*64 + arow)*DIM + sub*8;       \
            _Pragma("unroll")                                                   \
            for (int o = 0; o < 4; ++o){                                        \
                L[2*o]   = *(const float4*)(gp + o*64);                         \
                L[2*o+1] = *(const float4*)(gp + o*64 + 4);                     \
            }                                                                   \
        }

    #define COMPUTE8(buf, h)                                                    \
        {                                                                       \
            _Pragma("unroll")                                                   \
            for (int ks = 0; ks < 8; ++ks){                                     \
                bf16x8 a[4];                                                    \
                _Pragma("unroll")                                               \
                for (int ii = 0; ii < 4; ++ii)                                  \
                    a[ii] = *(const bf16x8*)&As[buf][ii*16 + l15][ks*32 + quad*8];\
                _Pragma("unroll")                                               \
                for (int ii = 0; ii < 4; ++ii)                                  \
                    _Pragma("unroll")                                           \
                    for (int jj = 0; jj < 2; ++jj){                             \
                        union { uint4 u; bf16x8 f; } bb;                        \
                        bb.u = Breg[jj][(h)*8 + ks];                            \
                        acc[ii][jj] = __builtin_amdgcn_mfma_f32_16x16x32_bf16(  \
                            a[ii], bb.f, acc[ii][jj], 0, 0, 0);                 \
                    }                                                           \
            }                                                                   \
        }

    WRITE_A(0);                 // waits the (0,h0) loads, converts, stores LDS
    __syncthreads();
    ISSUE_A(si, 0);             // (0,h1) in flight during first compute

    for (int c = 0; c < CCHUNKS; ++c){
        COMPUTE8(0, 0);
        WRITE_A(1);                              // consume (c,h1)
        __syncthreads();                         // β1
        if (c + 1 < CCHUNKS) ISSUE_A(sr, c+1);   // (c+1,h0) in flight
        COMPUTE8(1, 1);

        // per-wave epilogue: row partials -> red[w][*]
        #pragma unroll
        for (int ii = 0; ii < 4; ++ii)
            #pragma unroll
            for (int r = 0; r < 4; ++r){
                float v0 = acc[ii][0][r], v1 = acc[ii][1][r];
                float t = v0*v0 + v1*v1;
                t += __shfl_xor(t, 1);
                t += __shfl_xor(t, 2);
                t += __shfl_xor(t, 4);
                t += __shfl_xor(t, 8);
                if (l15 == 0) red[w][ii*16 + quad*4 + r] = t;
            }
        #pragma unroll
        for (int ii = 0; ii < 4; ++ii){ acc[ii][0] = vzero; acc[ii][1] = vzero; }

        if (c + 1 < CCHUNKS) WRITE_A(0);         // consume (c+1,h0)
        __syncthreads();                         // β2
        if (tid < 64){
            float o = red[0][tid] + red[1][tid] + red[2][tid] + red[3][tid]
                    + red[4][tid] + red[5][tid] + red[6][tid] + red[7][tid];
            out[mblock + c*64 + tid] = o;
        }
        if (c + 1 < CCHUNKS) ISSUE_A(si, c+1);   // (c+1,h1) in flight
    }
}

extern "C" void kernel_launch(void* const* d_in, const int* in_sizes, int n_in,
                              void* d_out, int out_size, void* d_ws, size_t ws_size,
                              hipStream_t stream){
    const float* params = (const float*)d_in[0];
    const float* sr     = (const float*)d_in[1];
    const float* si     = (const float*)d_in[2];
    unsigned short* G   = (unsigned short*)d_ws;   // 256*512*2 = 256 KB
    float* out          = (float*)d_out;

    build_g_kernel<<<dim3(DIM), dim3(256), 0, stream>>>(params, G);
    qform_kernel<<<dim3(GRID), dim3(512), 0, stream>>>(sr, si, G, out);
}